// Round 15
// baseline (214.943 us; speedup 1.0000x reference)
//
#include <hip/hip_runtime.h>
#include <hip/hip_bf16.h>
#include <stdint.h>

typedef __attribute__((ext_vector_type(4))) float f32x4;
typedef __attribute__((ext_vector_type(16))) float f32x16;
typedef __attribute__((ext_vector_type(8))) short bf16x8;
typedef __attribute__((ext_vector_type(4))) unsigned short u16x4;
typedef unsigned short u16;
typedef uint32_t u32;

#define B_ 4
#define S_ 2048
#define D_ 1024
#define H_ 16
#define DK_ 64
#define BS_ (B_*S_)       /* 8192 */
#define NQKV_ (3*H_*DK_)  /* 3072 */
#define NT_ (S_/64)       /* 32 i-tiles */

// 0.125 (1/sqrt(dk)) * log2(e): folded into Wq so softmax runs in exp2 domain
#define QSCALE 0.18033688011112042f

__device__ __forceinline__ u16 f2bf(float x) {
  union { float f; uint32_t u; } c; c.f = x;
  uint32_t r = (c.u + 0x7FFFu + ((c.u >> 16) & 1u)) >> 16;
  return (u16)r;
}

__device__ __forceinline__ float bf2f(u16 x) {
  union { uint32_t u; float f; } c; c.u = ((uint32_t)x) << 16;
  return c.f;
}

__device__ __forceinline__ float exp2_fast(float x) {
  float r; asm("v_exp_f32 %0, %1" : "=v"(r) : "v"(x)); return r;
}

// async global->LDS, 16B per lane; dest = wave-uniform base + lane*16
__device__ __forceinline__ void gl_lds16(const u16* g, u16* l) {
  __builtin_amdgcn_global_load_lds(
      (const __attribute__((address_space(1))) u32*)g,
      (__attribute__((address_space(3))) u32*)l, 16, 0, 0);
}

// Merged prep (one launch, internally concurrent):
//  bid<8192  : tokens f32->bf16
//  8192..8959: wcatT[n=3072][k=1024] (w*16+h)*64+dk <- W_w[h][d][dk] (*QSCALE Wq)
//  8960..9215: woT[1024][1024] = Wo^T bf16
__global__ __launch_bounds__(256) void prep_all(
    const float* __restrict__ tokens, const float* __restrict__ Wq,
    const float* __restrict__ Wk, const float* __restrict__ Wv,
    const float* __restrict__ Wo, u16* __restrict__ tok_bf,
    u16* __restrict__ wcatT, u16* __restrict__ woT) {
  const int bid = blockIdx.x;
  if (bid < 8192) {
    int i = (bid * 256 + threadIdx.x) * 4;
    const float* p = tokens + i;
    u16x4 o = { f2bf(p[0]), f2bf(p[1]), f2bf(p[2]), f2bf(p[3]) };
    *(u16x4*)(tok_bf + i) = o;
    return;
  }
  __shared__ float Tl[64][65];
  const int t = bid - 8192;
  if (t < 768) {
    const int y = t >> 4, xx = t & 15;      // y: 0..47 slice
    const int w = y >> 4, hh = y & 15;
    const int d0 = xx * 64;
    const float scale = (w == 0) ? QSCALE : 1.0f;
    const float* src = (w == 0 ? Wq : (w == 1 ? Wk : Wv)) + (long)hh * D_ * DK_;
    {
      int r = threadIdx.x >> 2, c = (threadIdx.x & 3) * 16;
      const float* g = src + (long)(d0 + r) * DK_ + c;
#pragma unroll
      for (int j = 0; j < 16; ++j) Tl[r][c + j] = g[j];
    }
    __syncthreads();
    {
      int dk = threadIdx.x >> 2, c = (threadIdx.x & 3) * 16;
      __attribute__((aligned(16))) u16 tmp[16];
#pragma unroll
      for (int j = 0; j < 16; ++j) tmp[j] = f2bf(Tl[c + j][dk] * scale);
      u16* o = wcatT + ((long)y * 64 + dk) * D_ + d0 + c;
      *(bf16x8*)o = *(const bf16x8*)&tmp[0];
      *(bf16x8*)(o + 8) = *(const bf16x8*)&tmp[8];
    }
  } else {
    const int t2 = t - 768;
    const int r0 = (t2 >> 4) * 64, c0 = (t2 & 15) * 64;
    {
      int r = threadIdx.x >> 2, c = (threadIdx.x & 3) * 16;
      const float* g = Wo + (long)(r0 + r) * D_ + c0 + c;
#pragma unroll
      for (int j = 0; j < 16; ++j) Tl[r][c + j] = g[j];
    }
    __syncthreads();
    {
      int rr = threadIdx.x >> 2, c = (threadIdx.x & 3) * 16;
      __attribute__((aligned(16))) u16 tmp[16];
#pragma unroll
      for (int j = 0; j < 16; ++j) tmp[j] = f2bf(Tl[c + j][rr]);
      u16* o = woT + (long)(c0 + rr) * D_ + r0 + c;
      *(bf16x8*)o = *(const bf16x8*)&tmp[0];
      *(bf16x8*)(o + 8) = *(const bf16x8*)&tmp[8];
    }
  }
}

// QKV GEMM: C[M,N] = A[M,K] * BT[N,K]^T. 128x256 tile, BK=32, 4 waves
// (wave output 64x128 -> 25% less LDS fragment traffic per output).
// Triple-buffered global_load_lds staging: ONE s_barrier + counted vmcnt(6).
// 2 blocks/CU (72KB LDS) keeps two independent barrier domains.
// Output bf16 into qkv; blocks with col0>=2048 write transposed into vt.
__global__ __launch_bounds__(256) void gemm_qkv(
    const u16* __restrict__ A, const u16* __restrict__ BT,
    u16* __restrict__ Cout, u16* __restrict__ vtout, int M, int N, int K) {
  __shared__ __attribute__((aligned(16))) u16 Al[3][128][32];
  __shared__ __attribute__((aligned(16))) u16 Bl[3][256][32];
  const int tid = threadIdx.x;
  const int wid = tid >> 6;           // 0..3
  const int lane = tid & 63;
  const int wm = (wid >> 1) * 64;     // 0 or 64
  const int wn = (wid & 1) * 128;     // 0 or 128
  const int row0 = blockIdx.x * 128;
  const int col0 = blockIdx.y * 256;
  const int fr = lane & 15;
  const int g = lane >> 4;            // logical k-chunk 0..3
  const int srow = lane >> 2;         // staging row within 16-row group
  const int sch = lane & 3;           // physical chunk 0..3

  // hoisted staging pointers: A 2 issues/wave (rows 32w..32w+32),
  // B 4 issues/wave (rows 64w..64w+64)
  const u16* aptr[2];
  const u16* bptr[4];
#pragma unroll
  for (int s = 0; s < 2; ++s) {
    int r = 32 * wid + 16 * s + srow;
    aptr[s] = A + (long)(row0 + r) * K + (sch ^ ((r >> 1) & 3)) * 8;
  }
#pragma unroll
  for (int s = 0; s < 4; ++s) {
    int r = 64 * wid + 16 * s + srow;
    bptr[s] = BT + (long)(col0 + r) * K + (sch ^ ((r >> 1) & 3)) * 8;
  }

  f32x4 acc[4][8] = {};
  const int nt = K >> 5;

#define GSTAGE(bufi)                                                           \
  { _Pragma("unroll")                                                          \
    for (int s = 0; s < 2; ++s) {                                              \
      gl_lds16(aptr[s], &Al[bufi][32 * wid + 16 * s][0]); aptr[s] += 32; }     \
    _Pragma("unroll")                                                          \
    for (int s = 0; s < 4; ++s) {                                              \
      gl_lds16(bptr[s], &Bl[bufi][64 * wid + 16 * s][0]); bptr[s] += 32; } }

  GSTAGE(0);
  for (int t = 0; t < nt; ++t) {
    const int cur = t % 3;
    if (t + 1 < nt) {
      GSTAGE((t + 1) % 3);
      asm volatile("s_waitcnt vmcnt(6)" ::: "memory");
    } else {
      asm volatile("s_waitcnt vmcnt(0)" ::: "memory");
    }
    __builtin_amdgcn_s_barrier();
    asm volatile("" ::: "memory");

    bf16x8 af[4], bfr[8];
#pragma unroll
    for (int mf = 0; mf < 4; ++mf) {
      int row = wm + mf * 16 + fr;
      af[mf] = *(const bf16x8*)&Al[cur][row][(g ^ ((row >> 1) & 3)) * 8];
    }
#pragma unroll
    for (int nf = 0; nf < 8; ++nf) {
      int row = wn + nf * 16 + fr;
      bfr[nf] = *(const bf16x8*)&Bl[cur][row][(g ^ ((row >> 1) & 3)) * 8];
    }
    __builtin_amdgcn_s_setprio(1);
#pragma unroll
    for (int mf = 0; mf < 4; ++mf)
#pragma unroll
      for (int nf = 0; nf < 8; ++nf)
        acc[mf][nf] = __builtin_amdgcn_mfma_f32_16x16x32_bf16(
            af[mf], bfr[nf], acc[mf][nf], 0, 0, 0);
    __builtin_amdgcn_s_setprio(0);
  }
#undef GSTAGE

  const int r0 = (lane >> 4) * 4;
  if (col0 >= 2048) {
    // V-head block: write transposed into vt[(b*16+h)*64+dv][i]
#pragma unroll
    for (int mf = 0; mf < 4; ++mf)
#pragma unroll
      for (int nf = 0; nf < 8; ++nf) {
        int colv = col0 + wn + nf * 16 + fr - 2048;
        long row = row0 + wm + mf * 16 + r0;
        int b2 = (int)(row >> 11);
        int i = (int)(row & 2047);
        u16x4 o = { f2bf(acc[mf][nf][0]), f2bf(acc[mf][nf][1]),
                    f2bf(acc[mf][nf][2]), f2bf(acc[mf][nf][3]) };
        *(u16x4*)(vtout + ((long)(b2 * 16 + (colv >> 6)) * 64 + (colv & 63)) * S_ + i) = o;
      }
    return;
  }
#pragma unroll
  for (int mf = 0; mf < 4; ++mf)
#pragma unroll
    for (int nf = 0; nf < 8; ++nf)
#pragma unroll
      for (int r = 0; r < 4; ++r) {
        long row = row0 + wm + mf * 16 + r0 + r;
        long col = col0 + wn + nf * 16 + fr;
        Cout[row * N + col] = f2bf(acc[mf][nf][r]);
      }
}

// Out-proj GEMM: C[M,N] = A[M,K]*BT[N,K]^T + resid (bf16), fp32 out.
// 128x128 tile, BK=32, 4 waves, triple-buffered, vmcnt(4), 3 blocks/CU.
__global__ __launch_bounds__(256) void gemm_out(
    const u16* __restrict__ A, const u16* __restrict__ BT,
    float* __restrict__ Cout, const u16* __restrict__ resid, int M, int N, int K) {
  __shared__ __attribute__((aligned(16))) u16 Al[3][128][32];
  __shared__ __attribute__((aligned(16))) u16 Bl[3][128][32];
  const int tid = threadIdx.x;
  const int wid = tid >> 6;
  const int lane = tid & 63;
  const int wm = (wid >> 1) * 64;
  const int wn = (wid & 1) * 64;
  const int row0 = blockIdx.x * 128;
  const int col0 = blockIdx.y * 128;
  const int fr = lane & 15;
  const int g = lane >> 4;
  const int srow = lane >> 2;
  const int sch = lane & 3;
  const int r0a = 32 * wid + srow;
  f32x4 acc[4][4] = {};

#define GSTAGE(bufi, kk)                                                       \
  { _Pragma("unroll")                                                          \
    for (int s = 0; s < 2; ++s) {                                              \
      int r = r0a + 16 * s;                                                    \
      int gc = (sch ^ ((r >> 1) & 3)) * 8;                                     \
      gl_lds16(A + (long)(row0 + r) * K + (kk) + gc, &Al[bufi][32 * wid + 16 * s][0]); \
      gl_lds16(BT + (long)(col0 + r) * K + (kk) + gc, &Bl[bufi][32 * wid + 16 * s][0]); \
    } }

  const int nt = K >> 5;
  GSTAGE(0, 0);
  for (int t = 0; t < nt; ++t) {
    const int cur = t % 3;
    if (t + 1 < nt) {
      GSTAGE((t + 1) % 3, (t + 1) << 5);
      asm volatile("s_waitcnt vmcnt(4)" ::: "memory");
    } else {
      asm volatile("s_waitcnt vmcnt(0)" ::: "memory");
    }
    __builtin_amdgcn_s_barrier();
    asm volatile("" ::: "memory");

    bf16x8 af[4], bfr[4];
#pragma unroll
    for (int mf = 0; mf < 4; ++mf) {
      int row = wm + mf * 16 + fr;
      af[mf] = *(const bf16x8*)&Al[cur][row][(g ^ ((row >> 1) & 3)) * 8];
    }
#pragma unroll
    for (int nf = 0; nf < 4; ++nf) {
      int row = wn + nf * 16 + fr;
      bfr[nf] = *(const bf16x8*)&Bl[cur][row][(g ^ ((row >> 1) & 3)) * 8];
    }
    __builtin_amdgcn_s_setprio(1);
#pragma unroll
    for (int mf = 0; mf < 4; ++mf)
#pragma unroll
      for (int nf = 0; nf < 4; ++nf)
        acc[mf][nf] = __builtin_amdgcn_mfma_f32_16x16x32_bf16(
            af[mf], bfr[nf], acc[mf][nf], 0, 0, 0);
    __builtin_amdgcn_s_setprio(0);
  }
#undef GSTAGE

  const int r0 = (lane >> 4) * 4;
#pragma unroll
  for (int mf = 0; mf < 4; ++mf)
#pragma unroll
    for (int nf = 0; nf < 4; ++nf)
#pragma unroll
      for (int r = 0; r < 4; ++r) {
        long row = row0 + wm + mf * 16 + r0 + r;
        long col = col0 + wn + nf * 16 + fr;
        Cout[row * N + col] = acc[mf][nf][r] + bf2f(resid[row * N + col]);
      }
}

// Flash attention, swapped roles (softmax over i):
//   O[j][d] = sum_i softmax_i(q_i.k_j * scale) V[i][d]
// 8 waves x 32 j. S^T = mfma(Qfrag,Kfrag): i in regs, j = lane&31.
// Static softmax (exp2 domain). Triple-buffered staging, 1 barrier/iter.
__global__ __launch_bounds__(512, 4) void attn_kernel(
    const u16* __restrict__ qkv, const u16* __restrict__ vt,
    u16* __restrict__ multi) {
  __shared__ __attribute__((aligned(16))) u16 smem[3][2][64][64]; // 48KB
  const int tid = threadIdx.x;
  const int wid = tid >> 6;          // 0..7
  const int lane = tid & 63;
  const int jl = lane & 31;
  const int h = lane >> 5;

  const int bid = blockIdx.x;
  const int bh = bid & 63;           // XCD affinity: xcd ~ bid%8 = bh%8
  const int jt = bid >> 6;           // 0..7
  const int b = bh >> 4, hh = bh & 15;
  const long rowb = (long)b * S_;
  const long rj0 = rowb + (long)jt * 256 + wid * 32;
  const int cbQ = hh * 64, cbK = (H_ + hh) * 64;

#define XF(r) (((r) ^ ((r) >> 3)) & 7)

  // K fragments (fixed per wave): K[j=jl][k=16ks+8h..]
  bf16x8 kf[4];
  const u16* kbase = qkv + (rj0 + jl) * NQKV_ + cbK + 8 * h;
#pragma unroll
  for (int ks = 0; ks < 4; ++ks) kf[ks] = *(const bf16x8*)(kbase + 16 * ks);

  // staging: each wave covers rows [8*wid, 8*wid+8) of the 64-row tile.
  const int strow = 8 * wid + (lane >> 3);
  const int stoff = ((lane & 7) ^ XF(strow)) * 8;
  const u16* qsrc = qkv + (rowb + strow) * NQKV_ + cbQ + stoff;
  const u16* vsrc = vt + ((long)bh * 64 + strow) * S_ + stoff;

  f32x16 accT0 = {}, accT1 = {};
  float l0 = 0.f, l1 = 0.f, l2 = 0.f, l3 = 0.f;

  // prologue: stage tile 0 into buf 0
  gl_lds16(qsrc, &smem[0][0][8 * wid][0]);
  gl_lds16(vsrc, &smem[0][1][8 * wid][0]);
  qsrc += (long)64 * NQKV_; vsrc += 64;

  for (int it = 0; it < NT_; ++it) {
    const int cur = it % 3;
    if (it + 1 < NT_) {
      const int nx = (it + 1) % 3;
      gl_lds16(qsrc, &smem[nx][0][8 * wid][0]);
      gl_lds16(vsrc, &smem[nx][1][8 * wid][0]);
      qsrc += (long)64 * NQKV_; vsrc += 64;
      asm volatile("s_waitcnt vmcnt(2)" ::: "memory");  // tile `it` landed
    } else {
      asm volatile("s_waitcnt vmcnt(0)" ::: "memory");
    }
    __builtin_amdgcn_s_barrier();
    asm volatile("" ::: "memory");

    // per-mb processing: st live range = 16 regs; PV(mb) overlaps QK(mb+1)
#pragma unroll
    for (int mb = 0; mb < 2; ++mb) {
      const int qrow = 32 * mb + jl;
      f32x16 st = {};
      __builtin_amdgcn_s_setprio(1);
#pragma unroll
      for (int ks = 0; ks < 4; ++ks) {
        bf16x8 qf = *(const bf16x8*)&smem[cur][0][qrow][((2 * ks + h) ^ XF(qrow)) * 8];
        st = __builtin_amdgcn_mfma_f32_32x32x16_bf16(qf, kf[ks], st, 0, 0, 0);
      }
      __builtin_amdgcn_s_setprio(0);

      // exp2 + pack; 4 partial l-chains (cross-half merge deferred)
      uint32_t q32[8];
#pragma unroll
      for (int rp = 0; rp < 8; ++rp) {
        float p0 = exp2_fast(st[2 * rp]);
        float p1 = exp2_fast(st[2 * rp + 1]);
        if (rp & 1) { l2 += p0; l3 += p1; } else { l0 += p0; l1 += p1; }
        __hip_bfloat162 bb = __float22bfloat162_rn(make_float2(p0, p1));
        uint32_t w; __builtin_memcpy(&w, &bb, 4);
        q32[rp] = w;
      }

      // PV for ks = 2*mb, 2*mb+1
      __builtin_amdgcn_s_setprio(1);
#pragma unroll
      for (int t2 = 0; t2 < 2; ++t2) {
        const int ks = 2 * mb + t2;
        uint32_t a0 = q32[4 * t2 + 0], b0 = q32[4 * t2 + 1];
        uint32_t a1 = q32[4 * t2 + 2], b1 = q32[4 * t2 + 3];
        asm("v_permlane32_swap_b32 %0, %1" : "+v"(a0), "+v"(a1));
        asm("v_permlane32_swap_b32 %0, %1" : "+v"(b0), "+v"(b1));
        union { bf16x8 v; uint32_t u[4]; } pa;
        pa.u[0] = a0; pa.u[1] = b0; pa.u[2] = a1; pa.u[3] = b1;
        bf16x8 vf0 = *(const bf16x8*)&smem[cur][1][jl][((2 * ks + h) ^ XF(jl)) * 8];
        bf16x8 vf1 = *(const bf16x8*)&smem[cur][1][32 + jl][((2 * ks + h) ^ XF(32 + jl)) * 8];
        accT0 = __builtin_amdgcn_mfma_f32_32x32x16_bf16(vf0, pa.v, accT0, 0, 0, 0);
        accT1 = __builtin_amdgcn_mfma_f32_32x32x16_bf16(vf1, pa.v, accT1, 0, 0, 0);
      }
      __builtin_amdgcn_s_setprio(0);
    }
  }
#undef XF

  __syncthreads();   // all waves done with smem: reuse as epilogue buffer
  u16 (*Wl)[32][72] = (u16 (*)[32][72])&smem[0][0][0][0];
  float lsum = (l0 + l2) + (l1 + l3);
  lsum += __shfl_xor(lsum, 32);
  float inv = 1.f / lsum;
#pragma unroll
  for (int r = 0; r < 16; ++r) {
    int d = (r & 3) + 8 * (r >> 2) + 4 * h;
    Wl[wid][jl][d] = f2bf(accT0[r] * inv);
    Wl[wid][jl][32 + d] = f2bf(accT1[r] * inv);
  }
  // same-wave LDS write->read ordering
  int j2 = lane >> 1, dh = (lane & 1) * 32;
#pragma unroll
  for (int c = 0; c < 4; ++c) {
    bf16x8 vrow = *(const bf16x8*)&Wl[wid][j2][dh + 8 * c];
    *(bf16x8*)(multi + (rj0 + j2) * (H_ * DK_) + hh * 64 + dh + 8 * c) = vrow;
  }
}

// In-place LayerNorm over rows of 1024 fp32
__global__ __launch_bounds__(256) void ln_kernel(
    float* __restrict__ out, const float* __restrict__ gamma,
    const float* __restrict__ beta) {
  const int tid = threadIdx.x;
  const int wid = tid >> 6;
  const int lane = tid & 63;
  float* p = out + (long)blockIdx.x * D_;
  const float* pv = p + tid * 4;
  float x0 = pv[0], x1 = pv[1], x2 = pv[2], x3 = pv[3];
  float s = x0 + x1 + x2 + x3;
  float q = x0 * x0 + x1 * x1 + x2 * x2 + x3 * x3;
#pragma unroll
  for (int off = 32; off > 0; off >>= 1) {
    s += __shfl_down(s, off);
    q += __shfl_down(q, off);
  }
  __shared__ float sh[8];
  if (lane == 0) { sh[wid] = s; sh[4 + wid] = q; }
  __syncthreads();
  s = sh[0] + sh[1] + sh[2] + sh[3];
  q = sh[4] + sh[5] + sh[6] + sh[7];
  float mean = s * (1.0f / D_);
  float var = q * (1.0f / D_) - mean * mean;
  float rstd = rsqrtf(var + 1e-5f);
  const float* g = gamma + tid * 4;
  const float* be = beta + tid * 4;
  float* po = p + tid * 4;
  po[0] = (x0 - mean) * rstd * g[0] + be[0];
  po[1] = (x1 - mean) * rstd * g[1] + be[1];
  po[2] = (x2 - mean) * rstd * g[2] + be[2];
  po[3] = (x3 - mean) * rstd * g[3] + be[3];
}

extern "C" void kernel_launch(void* const* d_in, const int* in_sizes, int n_in,
                              void* d_out, int out_size, void* d_ws, size_t ws_size,
                              hipStream_t stream) {
  const float* tokens = (const float*)d_in[0];
  const float* Wq = (const float*)d_in[1];
  const float* Wk = (const float*)d_in[2];
  const float* Wv = (const float*)d_in[3];
  const float* Wo = (const float*)d_in[4];
  const float* gamma = (const float*)d_in[5];
  const float* beta = (const float*)d_in[6];
  float* out = (float*)d_out;

  char* ws = (char*)d_ws;
  u16* tok_bf = (u16*)(ws);                    // 16 MB  [8192][1024]
  u16* wcatT  = (u16*)(ws + 16777216);         // 6 MB   [3072][1024]
  u16* woT    = (u16*)(ws + 23068672);         // 2 MB   [1024][1024]
  u16* qkv    = (u16*)(ws + 25165824);         // 48 MB  [8192][3072] (V third unused)
  u16* multi  = (u16*)(ws + 75497472);         // 16 MB  [8192][1024]
  u16* vt     = (u16*)(ws + 92274688);         // 16 MB  [64][64][2048]

  prep_all<<<9216, 256, 0, stream>>>(tokens, Wq, Wk, Wv, Wo, tok_bf, wcatT, woT);

  // QKV projection (128x256 tile); V-head blocks write transposed into vt
  gemm_qkv<<<dim3(BS_ / 128, NQKV_ / 256), 256, 0, stream>>>(
      tok_bf, wcatT, qkv, vt, BS_, NQKV_, D_);

  attn_kernel<<<512, 512, 0, stream>>>(qkv, vt, multi);

  gemm_out<<<dim3(BS_ / 128, D_ / 128), 256, 0, stream>>>(
      multi, woT, out, tok_bf, BS_, D_, D_);

  ln_kernel<<<BS_, 256, 0, stream>>>(out, gamma, beta);
}

// Round 16
// 193.501 us; speedup vs baseline: 1.1108x; 1.1108x over previous
//
#include <hip/hip_runtime.h>
#include <hip/hip_bf16.h>
#include <stdint.h>

typedef __attribute__((ext_vector_type(4))) float f32x4;
typedef __attribute__((ext_vector_type(16))) float f32x16;
typedef __attribute__((ext_vector_type(8))) short bf16x8;
typedef __attribute__((ext_vector_type(4))) unsigned short u16x4;
typedef unsigned short u16;
typedef uint32_t u32;

#define B_ 4
#define S_ 2048
#define D_ 1024
#define H_ 16
#define DK_ 64
#define BS_ (B_*S_)       /* 8192 */
#define NQKV_ (3*H_*DK_)  /* 3072 */
#define NT_ (S_/64)       /* 32 i-tiles */

// 0.125 (1/sqrt(dk)) * log2(e): folded into Wq so softmax runs in exp2 domain
#define QSCALE 0.18033688011112042f

__device__ __forceinline__ u16 f2bf(float x) {
  union { float f; uint32_t u; } c; c.f = x;
  uint32_t r = (c.u + 0x7FFFu + ((c.u >> 16) & 1u)) >> 16;
  return (u16)r;
}

__device__ __forceinline__ float bf2f(u16 x) {
  union { uint32_t u; float f; } c; c.u = ((uint32_t)x) << 16;
  return c.f;
}

__device__ __forceinline__ float exp2_fast(float x) {
  float r; asm("v_exp_f32 %0, %1" : "=v"(r) : "v"(x)); return r;
}

// async global->LDS, 16B per lane; dest = wave-uniform base + lane*16
__device__ __forceinline__ void gl_lds16(const u16* g, u16* l) {
  __builtin_amdgcn_global_load_lds(
      (const __attribute__((address_space(1))) u32*)g,
      (__attribute__((address_space(3))) u32*)l, 16, 0, 0);
}

// Merged prep (one launch, internally concurrent):
//  bid<8192  : tokens f32->bf16
//  8192..8959: wcatT[n=3072][k=1024] (w*16+h)*64+dk <- W_w[h][d][dk] (*QSCALE Wq)
//  8960..9215: woT[1024][1024] = Wo^T bf16
__global__ __launch_bounds__(256) void prep_all(
    const float* __restrict__ tokens, const float* __restrict__ Wq,
    const float* __restrict__ Wk, const float* __restrict__ Wv,
    const float* __restrict__ Wo, u16* __restrict__ tok_bf,
    u16* __restrict__ wcatT, u16* __restrict__ woT) {
  const int bid = blockIdx.x;
  if (bid < 8192) {
    int i = (bid * 256 + threadIdx.x) * 4;
    const float* p = tokens + i;
    u16x4 o = { f2bf(p[0]), f2bf(p[1]), f2bf(p[2]), f2bf(p[3]) };
    *(u16x4*)(tok_bf + i) = o;
    return;
  }
  __shared__ float Tl[64][65];
  const int t = bid - 8192;
  if (t < 768) {
    const int y = t >> 4, xx = t & 15;      // y: 0..47 slice
    const int w = y >> 4, hh = y & 15;
    const int d0 = xx * 64;
    const float scale = (w == 0) ? QSCALE : 1.0f;
    const float* src = (w == 0 ? Wq : (w == 1 ? Wk : Wv)) + (long)hh * D_ * DK_;
    {
      int r = threadIdx.x >> 2, c = (threadIdx.x & 3) * 16;
      const float* g = src + (long)(d0 + r) * DK_ + c;
#pragma unroll
      for (int j = 0; j < 16; ++j) Tl[r][c + j] = g[j];
    }
    __syncthreads();
    {
      int dk = threadIdx.x >> 2, c = (threadIdx.x & 3) * 16;
      __attribute__((aligned(16))) u16 tmp[16];
#pragma unroll
      for (int j = 0; j < 16; ++j) tmp[j] = f2bf(Tl[c + j][dk] * scale);
      u16* o = wcatT + ((long)y * 64 + dk) * D_ + d0 + c;
      *(bf16x8*)o = *(const bf16x8*)&tmp[0];
      *(bf16x8*)(o + 8) = *(const bf16x8*)&tmp[8];
    }
  } else {
    const int t2 = t - 768;
    const int r0 = (t2 >> 4) * 64, c0 = (t2 & 15) * 64;
    {
      int r = threadIdx.x >> 2, c = (threadIdx.x & 3) * 16;
      const float* g = Wo + (long)(r0 + r) * D_ + c0 + c;
#pragma unroll
      for (int j = 0; j < 16; ++j) Tl[r][c + j] = g[j];
    }
    __syncthreads();
    {
      int rr = threadIdx.x >> 2, c = (threadIdx.x & 3) * 16;
      __attribute__((aligned(16))) u16 tmp[16];
#pragma unroll
      for (int j = 0; j < 16; ++j) tmp[j] = f2bf(Tl[c + j][rr]);
      u16* o = woT + (long)(c0 + rr) * D_ + r0 + c;
      *(bf16x8*)o = *(const bf16x8*)&tmp[0];
      *(bf16x8*)(o + 8) = *(const bf16x8*)&tmp[8];
    }
  }
}

// GEMM: C[M,N] = A[M,K] * BT[N,K]^T. 128x128 tile, BK=32.
// Triple-buffered global_load_lds staging: ONE s_barrier + counted vmcnt(4).
// VSPLIT: blocks with col0>=2048 write output transposed into vt (V heads).
// resid (if non-null) is bf16 tok_bf.
template<bool OUT_BF16, bool VSPLIT>
__global__ __launch_bounds__(256) void gemm_bf16(
    const u16* __restrict__ A, const u16* __restrict__ BT,
    void* __restrict__ Cout, const u16* __restrict__ resid,
    u16* __restrict__ vtout, int M, int N, int K) {
  __shared__ __attribute__((aligned(16))) u16 Al[3][128][32];
  __shared__ __attribute__((aligned(16))) u16 Bl[3][128][32];
  const int tid = threadIdx.x;
  const int wid = tid >> 6;
  const int lane = tid & 63;
  const int wm = (wid >> 1) * 64;
  const int wn = (wid & 1) * 64;
  const int row0 = blockIdx.x * 128;
  const int col0 = blockIdx.y * 128;
  const int fr = lane & 15;
  const int g = lane >> 4;            // logical k-chunk 0..3

  const int srow = lane >> 2;         // staging: row within 16-row group
  const int sch = lane & 3;           // physical chunk 0..3
  const int r0a = 32 * wid + srow;
  f32x4 acc[4][4] = {};

#define GSTAGE(bufi, kk)                                                       \
  {                                                                            \
    _Pragma("unroll")                                                          \
    for (int s = 0; s < 2; ++s) {                                              \
      int r = r0a + 16 * s;                                                    \
      int gc = (sch ^ ((r >> 1) & 3)) * 8;                                     \
      gl_lds16(A + (long)(row0 + r) * K + (kk) + gc, &Al[bufi][32 * wid + 16 * s][0]); \
      gl_lds16(BT + (long)(col0 + r) * K + (kk) + gc, &Bl[bufi][32 * wid + 16 * s][0]); \
    }                                                                          \
  }

  const int nt = K >> 5;
  GSTAGE(0, 0);

  for (int t = 0; t < nt; ++t) {
    const int cur = t % 3;
    if (t + 1 < nt) {
      GSTAGE((t + 1) % 3, (t + 1) << 5);
      asm volatile("s_waitcnt vmcnt(4)" ::: "memory");
    } else {
      asm volatile("s_waitcnt vmcnt(0)" ::: "memory");
    }
    __builtin_amdgcn_s_barrier();
    asm volatile("" ::: "memory");

    bf16x8 af[4], bfr[4];
#pragma unroll
    for (int mf = 0; mf < 4; ++mf) {
      int row = wm + mf * 16 + fr;
      af[mf] = *(const bf16x8*)&Al[cur][row][(g ^ ((row >> 1) & 3)) * 8];
    }
#pragma unroll
    for (int nf = 0; nf < 4; ++nf) {
      int row = wn + nf * 16 + fr;
      bfr[nf] = *(const bf16x8*)&Bl[cur][row][(g ^ ((row >> 1) & 3)) * 8];
    }
    __builtin_amdgcn_s_setprio(1);
#pragma unroll
    for (int mf = 0; mf < 4; ++mf)
#pragma unroll
      for (int nf = 0; nf < 4; ++nf)
        acc[mf][nf] = __builtin_amdgcn_mfma_f32_16x16x32_bf16(
            af[mf], bfr[nf], acc[mf][nf], 0, 0, 0);
    __builtin_amdgcn_s_setprio(0);
  }
#undef GSTAGE

  const int r0 = (lane >> 4) * 4;
  if constexpr (VSPLIT) {
    if (col0 >= 2048) {
#pragma unroll
      for (int mf = 0; mf < 4; ++mf)
#pragma unroll
        for (int nf = 0; nf < 4; ++nf) {
          int colv = col0 + wn + nf * 16 + fr - 2048;
          long row = row0 + wm + mf * 16 + r0;
          int b2 = (int)(row >> 11);
          int i = (int)(row & 2047);
          u16x4 o = { f2bf(acc[mf][nf][0]), f2bf(acc[mf][nf][1]),
                      f2bf(acc[mf][nf][2]), f2bf(acc[mf][nf][3]) };
          *(u16x4*)(vtout + ((long)(b2 * 16 + (colv >> 6)) * 64 + (colv & 63)) * S_ + i) = o;
        }
      return;
    }
  }
#pragma unroll
  for (int mf = 0; mf < 4; ++mf)
#pragma unroll
    for (int nf = 0; nf < 4; ++nf)
#pragma unroll
      for (int r = 0; r < 4; ++r) {
        long row = row0 + wm + mf * 16 + r0 + r;
        long col = col0 + wn + nf * 16 + fr;
        if constexpr (OUT_BF16) {
          ((u16*)Cout)[row * N + col] = f2bf(acc[mf][nf][r]);
        } else {
          float v = acc[mf][nf][r] + bf2f(resid[row * N + col]);
          ((float*)Cout)[row * N + col] = v;
        }
      }
}

// Flash attention, swapped roles (softmax over i):
//   O[j][d] = sum_i softmax_i(q_i.k_j * scale) V[i][d]
// 8 waves x 32 j. S^T = mfma(Qfrag,Kfrag): i in regs, j = lane&31.
// Static softmax (exp2 domain). Triple-buffered staging, 1 barrier/iter.
// mb-split processing keeps score-state live range at 16 regs; cross-half
// l reduction deferred to the epilogue.
__global__ __launch_bounds__(512, 4) void attn_kernel(
    const u16* __restrict__ qkv, const u16* __restrict__ vt,
    u16* __restrict__ multi) {
  __shared__ __attribute__((aligned(16))) u16 smem[3][2][64][64]; // 48KB
  const int tid = threadIdx.x;
  const int wid = tid >> 6;          // 0..7
  const int lane = tid & 63;
  const int jl = lane & 31;
  const int h = lane >> 5;

  const int bid = blockIdx.x;
  const int bh = bid & 63;           // XCD affinity: xcd ~ bid%8 = bh%8
  const int jt = bid >> 6;           // 0..7
  const int b = bh >> 4, hh = bh & 15;
  const long rowb = (long)b * S_;
  const long rj0 = rowb + (long)jt * 256 + wid * 32;
  const int cbQ = hh * 64, cbK = (H_ + hh) * 64;

#define XF(r) (((r) ^ ((r) >> 3)) & 7)

  // K fragments (fixed per wave): K[j=jl][k=16ks+8h..]
  bf16x8 kf[4];
  const u16* kbase = qkv + (rj0 + jl) * NQKV_ + cbK + 8 * h;
#pragma unroll
  for (int ks = 0; ks < 4; ++ks) kf[ks] = *(const bf16x8*)(kbase + 16 * ks);

  // staging: each wave covers rows [8*wid, 8*wid+8) of the 64-row tile.
  const int strow = 8 * wid + (lane >> 3);
  const int stoff = ((lane & 7) ^ XF(strow)) * 8;
  const u16* qsrc = qkv + (rowb + strow) * NQKV_ + cbQ + stoff;
  const u16* vsrc = vt + ((long)bh * 64 + strow) * S_ + stoff;

  f32x16 accT0 = {}, accT1 = {};
  float l0 = 0.f, l1 = 0.f, l2 = 0.f, l3 = 0.f;

  // prologue: stage tile 0 into buf 0
  gl_lds16(qsrc, &smem[0][0][8 * wid][0]);
  gl_lds16(vsrc, &smem[0][1][8 * wid][0]);
  qsrc += (long)64 * NQKV_; vsrc += 64;

  for (int it = 0; it < NT_; ++it) {
    const int cur = it % 3;
    if (it + 1 < NT_) {
      const int nx = (it + 1) % 3;
      gl_lds16(qsrc, &smem[nx][0][8 * wid][0]);
      gl_lds16(vsrc, &smem[nx][1][8 * wid][0]);
      qsrc += (long)64 * NQKV_; vsrc += 64;
      asm volatile("s_waitcnt vmcnt(2)" ::: "memory");  // tile `it` landed
    } else {
      asm volatile("s_waitcnt vmcnt(0)" ::: "memory");
    }
    __builtin_amdgcn_s_barrier();
    asm volatile("" ::: "memory");

    // per-mb processing: st live range = 16 regs; PV(mb) overlaps QK(mb+1)
#pragma unroll
    for (int mb = 0; mb < 2; ++mb) {
      const int qrow = 32 * mb + jl;
      f32x16 st = {};
      __builtin_amdgcn_s_setprio(1);
#pragma unroll
      for (int ks = 0; ks < 4; ++ks) {
        bf16x8 qf = *(const bf16x8*)&smem[cur][0][qrow][((2 * ks + h) ^ XF(qrow)) * 8];
        st = __builtin_amdgcn_mfma_f32_32x32x16_bf16(qf, kf[ks], st, 0, 0, 0);
      }
      __builtin_amdgcn_s_setprio(0);

      // exp2 + pack; 4 partial l-chains (cross-half merge deferred)
      uint32_t q32[8];
#pragma unroll
      for (int rp = 0; rp < 8; ++rp) {
        float p0 = exp2_fast(st[2 * rp]);
        float p1 = exp2_fast(st[2 * rp + 1]);
        if (rp & 1) { l2 += p0; l3 += p1; } else { l0 += p0; l1 += p1; }
        __hip_bfloat162 bb = __float22bfloat162_rn(make_float2(p0, p1));
        uint32_t w; __builtin_memcpy(&w, &bb, 4);
        q32[rp] = w;
      }

      // PV for ks = 2*mb, 2*mb+1
      __builtin_amdgcn_s_setprio(1);
#pragma unroll
      for (int t2 = 0; t2 < 2; ++t2) {
        const int ks = 2 * mb + t2;
        uint32_t a0 = q32[4 * t2 + 0], b0 = q32[4 * t2 + 1];
        uint32_t a1 = q32[4 * t2 + 2], b1 = q32[4 * t2 + 3];
        asm("v_permlane32_swap_b32 %0, %1" : "+v"(a0), "+v"(a1));
        asm("v_permlane32_swap_b32 %0, %1" : "+v"(b0), "+v"(b1));
        union { bf16x8 v; uint32_t u[4]; } pa;
        pa.u[0] = a0; pa.u[1] = b0; pa.u[2] = a1; pa.u[3] = b1;
        bf16x8 vf0 = *(const bf16x8*)&smem[cur][1][jl][((2 * ks + h) ^ XF(jl)) * 8];
        bf16x8 vf1 = *(const bf16x8*)&smem[cur][1][32 + jl][((2 * ks + h) ^ XF(32 + jl)) * 8];
        accT0 = __builtin_amdgcn_mfma_f32_32x32x16_bf16(vf0, pa.v, accT0, 0, 0, 0);
        accT1 = __builtin_amdgcn_mfma_f32_32x32x16_bf16(vf1, pa.v, accT1, 0, 0, 0);
      }
      __builtin_amdgcn_s_setprio(0);
    }
  }
#undef XF

  __syncthreads();   // all waves done with smem: reuse as epilogue buffer
  u16 (*Wl)[32][72] = (u16 (*)[32][72])&smem[0][0][0][0];
  float lsum = (l0 + l2) + (l1 + l3);
  lsum += __shfl_xor(lsum, 32);
  float inv = 1.f / lsum;
#pragma unroll
  for (int r = 0; r < 16; ++r) {
    int d = (r & 3) + 8 * (r >> 2) + 4 * h;
    Wl[wid][jl][d] = f2bf(accT0[r] * inv);
    Wl[wid][jl][32 + d] = f2bf(accT1[r] * inv);
  }
  // same-wave LDS write->read ordering
  int j2 = lane >> 1, dh = (lane & 1) * 32;
#pragma unroll
  for (int c = 0; c < 4; ++c) {
    bf16x8 vrow = *(const bf16x8*)&Wl[wid][j2][dh + 8 * c];
    *(bf16x8*)(multi + (rj0 + j2) * (H_ * DK_) + hh * 64 + dh + 8 * c) = vrow;
  }
}

// In-place LayerNorm over rows of 1024 fp32
__global__ __launch_bounds__(256) void ln_kernel(
    float* __restrict__ out, const float* __restrict__ gamma,
    const float* __restrict__ beta) {
  const int tid = threadIdx.x;
  const int wid = tid >> 6;
  const int lane = tid & 63;
  float* p = out + (long)blockIdx.x * D_;
  const float* pv = p + tid * 4;
  float x0 = pv[0], x1 = pv[1], x2 = pv[2], x3 = pv[3];
  float s = x0 + x1 + x2 + x3;
  float q = x0 * x0 + x1 * x1 + x2 * x2 + x3 * x3;
#pragma unroll
  for (int off = 32; off > 0; off >>= 1) {
    s += __shfl_down(s, off);
    q += __shfl_down(q, off);
  }
  __shared__ float sh[8];
  if (lane == 0) { sh[wid] = s; sh[4 + wid] = q; }
  __syncthreads();
  s = sh[0] + sh[1] + sh[2] + sh[3];
  q = sh[4] + sh[5] + sh[6] + sh[7];
  float mean = s * (1.0f / D_);
  float var = q * (1.0f / D_) - mean * mean;
  float rstd = rsqrtf(var + 1e-5f);
  const float* g = gamma + tid * 4;
  const float* be = beta + tid * 4;
  float* po = p + tid * 4;
  po[0] = (x0 - mean) * rstd * g[0] + be[0];
  po[1] = (x1 - mean) * rstd * g[1] + be[1];
  po[2] = (x2 - mean) * rstd * g[2] + be[2];
  po[3] = (x3 - mean) * rstd * g[3] + be[3];
}

extern "C" void kernel_launch(void* const* d_in, const int* in_sizes, int n_in,
                              void* d_out, int out_size, void* d_ws, size_t ws_size,
                              hipStream_t stream) {
  const float* tokens = (const float*)d_in[0];
  const float* Wq = (const float*)d_in[1];
  const float* Wk = (const float*)d_in[2];
  const float* Wv = (const float*)d_in[3];
  const float* Wo = (const float*)d_in[4];
  const float* gamma = (const float*)d_in[5];
  const float* beta = (const float*)d_in[6];
  float* out = (float*)d_out;

  char* ws = (char*)d_ws;
  u16* tok_bf = (u16*)(ws);                    // 16 MB  [8192][1024]
  u16* wcatT  = (u16*)(ws + 16777216);         // 6 MB   [3072][1024]
  u16* woT    = (u16*)(ws + 23068672);         // 2 MB   [1024][1024]
  u16* qkv    = (u16*)(ws + 25165824);         // 48 MB  [8192][3072] (V third unused)
  u16* multi  = (u16*)(ws + 75497472);         // 16 MB  [8192][1024]
  u16* vt     = (u16*)(ws + 92274688);         // 16 MB  [64][64][2048]

  prep_all<<<9216, 256, 0, stream>>>(tokens, Wq, Wk, Wv, Wo, tok_bf, wcatT, woT);

  // QKV projection; V-head blocks write transposed into vt directly
  gemm_bf16<true, true><<<dim3(BS_ / 128, NQKV_ / 128), 256, 0, stream>>>(
      tok_bf, wcatT, qkv, nullptr, vt, BS_, NQKV_, D_);

  attn_kernel<<<512, 512, 0, stream>>>(qkv, vt, multi);

  gemm_bf16<false, false><<<dim3(BS_ / 128, D_ / 128), 256, 0, stream>>>(
      multi, woT, out, tok_bf, nullptr, BS_, D_, D_);

  ln_kernel<<<BS_, 256, 0, stream>>>(out, gamma, beta);
}